// Round 5
// baseline (313.986 us; speedup 1.0000x reference)
//
#include <hip/hip_runtime.h>
#include <math.h>

#define EPSV 1.1920929e-07f

typedef __attribute__((ext_vector_type(8))) short short8;
typedef __attribute__((ext_vector_type(4))) float f32x4;

__device__ __forceinline__ float bf2f(unsigned short u) {
    union { unsigned int i; float f; } c; c.i = ((unsigned int)u) << 16; return c.f;
}
__device__ __forceinline__ unsigned short f2bf(float f) {
    union { float f; unsigned int i; } c; c.f = f;
    unsigned int r = c.i + 0x7FFFu + ((c.i >> 16) & 1u);   // RNE
    return (unsigned short)(r >> 16);
}
// pack two f32 -> two bf16 (round-half-up) in one u32: low=a, high=b
__device__ __forceinline__ unsigned int pack_bf16_ru(float a, float b) {
    union { float f; unsigned int i; } ca, cb; ca.f = a; cb.f = b;
    return __builtin_amdgcn_perm(cb.i + 0x8000u, ca.i + 0x8000u, 0x07060302u);
}
// async global -> LDS, 16 B per lane (dest = wave-uniform base + lane*16)
__device__ __forceinline__ void async_lds16(const unsigned short* g, unsigned short* l) {
    __builtin_amdgcn_global_load_lds(
        (const __attribute__((address_space(1))) unsigned int*)g,
        (__attribute__((address_space(3))) unsigned int*)l, 16, 0, 0);
}

// ======================================================================
// cast fp32 -> bf16 elementwise. 4 elems/thread.
// ======================================================================
__global__ __launch_bounds__(256) void cast_bf16(
    const float* __restrict__ src, unsigned short* __restrict__ dst, int n)
{
    const int i = (blockIdx.x * 256 + threadIdx.x) * 4;
    if (i >= n) return;
    const float4 v = *(const float4*)&src[i];
    ushort4 o;
    o.x = f2bf(v.x); o.y = f2bf(v.y); o.z = f2bf(v.z); o.w = f2bf(v.w);
    *(ushort4*)&dst[i] = o;
}

// ======================================================================
// transpose + cast: W [K][N] fp32 -> Wt [N][K] bf16. 32x32 tiles.
// ======================================================================
__global__ __launch_bounds__(256) void transpose_cast(
    const float* __restrict__ W, unsigned short* __restrict__ Wt, int K, int N)
{
    __shared__ float tile[32][33];
    const int n0 = blockIdx.x * 32, k0 = blockIdx.y * 32;
    const int r = threadIdx.x >> 3, c4 = (threadIdx.x & 7) * 4;
    const float4 v = *(const float4*)&W[(size_t)(k0 + r) * N + n0 + c4];
    tile[r][c4 + 0] = v.x; tile[r][c4 + 1] = v.y;
    tile[r][c4 + 2] = v.z; tile[r][c4 + 3] = v.w;
    __syncthreads();
    ushort4 o;
    o.x = f2bf(tile[c4 + 0][r]); o.y = f2bf(tile[c4 + 1][r]);
    o.z = f2bf(tile[c4 + 2][r]); o.w = f2bf(tile[c4 + 3][r]);
    *(ushort4*)&Wt[(size_t)(n0 + r) * K + k0 + c4] = o;
}

// ======================================================================
// bf16 MFMA GEMM, m97 structure: C[M,N] = A[M,K] @ Bt[N,K]^T + bias[N]
// 128x128x32 tile; global_load_lds width-16 staging into unpadded
// [128][32] LDS (dest = wave base + lane*16, matched layout).
// ======================================================================
template <bool OUT_BF16>
__global__ __launch_bounds__(256) void gemm_bf16(
    const unsigned short* __restrict__ A,
    const unsigned short* __restrict__ Bt,
    const float* __restrict__ bias,
    void* __restrict__ Cv,
    int M, int N, int K)
{
    __shared__ unsigned short As[128][32];
    __shared__ unsigned short Bs[128][32];
    const int t    = threadIdx.x;
    const int lane = t & 63;
    const int wv   = t >> 6;
    const int wrow = (wv >> 1) * 64;
    const int wcol = (wv & 1) * 64;
    const int m0 = blockIdx.y * 128;
    const int n0 = blockIdx.x * 128;
    const int col  = lane & 15;
    const int quad = lane >> 4;

    const int srow = (wv << 5) + (lane >> 2);     // wv*32 + 0..15
    const int scol = (lane & 3) << 3;             // 0,8,16,24
    const unsigned short* ap0 = A  + (size_t)(m0 + srow) * K + scol;
    const unsigned short* ap1 = ap0 + (size_t)16 * K;
    const unsigned short* bp0 = Bt + (size_t)(n0 + srow) * K + scol;
    const unsigned short* bp1 = bp0 + (size_t)16 * K;
    unsigned short* al0 = &As[srow][scol];
    unsigned short* al1 = &As[srow + 16][scol];
    unsigned short* bl0 = &Bs[srow][scol];
    unsigned short* bl1 = &Bs[srow + 16][scol];

    f32x4 acc[4][4];
    #pragma unroll
    for (int i = 0; i < 4; ++i)
        #pragma unroll
        for (int j = 0; j < 4; ++j)
            acc[i][j] = (f32x4){0.f, 0.f, 0.f, 0.f};

    for (int k0 = 0; k0 < K; k0 += 32) {
        async_lds16(ap0, al0);
        async_lds16(ap1, al1);
        async_lds16(bp0, bl0);
        async_lds16(bp1, bl1);
        ap0 += 32; ap1 += 32; bp0 += 32; bp1 += 32;
        __syncthreads();
        short8 af[4], bf[4];
        #pragma unroll
        for (int mt = 0; mt < 4; ++mt)
            af[mt] = *(const short8*)&As[wrow + mt * 16 + col][quad << 3];
        #pragma unroll
        for (int nt = 0; nt < 4; ++nt)
            bf[nt] = *(const short8*)&Bs[wcol + nt * 16 + col][quad << 3];
        #pragma unroll
        for (int mt = 0; mt < 4; ++mt)
            #pragma unroll
            for (int nt = 0; nt < 4; ++nt)
                acc[mt][nt] = __builtin_amdgcn_mfma_f32_16x16x32_bf16(
                    af[mt], bf[nt], acc[mt][nt], 0, 0, 0);
        __syncthreads();
    }

    const int rowq = quad << 2;
    #pragma unroll
    for (int nt = 0; nt < 4; ++nt) {
        const int n = n0 + wcol + nt * 16 + col;
        const float bv = bias[n];
        #pragma unroll
        for (int mt = 0; mt < 4; ++mt) {
            #pragma unroll
            for (int r = 0; r < 4; ++r) {
                const int m = m0 + wrow + mt * 16 + rowq + r;
                const float v = acc[mt][nt][r] + bv;
                if (OUT_BF16)
                    ((unsigned short*)Cv)[(size_t)m * N + n] = f2bf(v);
                else
                    ((float*)Cv)[(size_t)m * N + n] = v;
            }
        }
    }
}

// ======================================================================
// RMSNorm (D=64) then rotary, in-place on bf16 q/k slices.
// q output pre-scaled by log2e/8 (folded softmax scale -> exp2 domain).
// ======================================================================
__global__ __launch_bounds__(256) void rmsnorm_rope(
    unsigned short* __restrict__ qkv, const float* __restrict__ cosp,
    const float* __restrict__ sinp, int BT, int T)
{
    const int wid  = (blockIdx.x << 2) + (threadIdx.x >> 6);
    const int lane = threadIdx.x & 63;
    const int w  = wid & 1;
    const int h  = (wid >> 1) & 15;
    const int bt = wid >> 5;
    if (bt >= BT) return;
    const int tpos = bt % T;
    const size_t idx = (size_t)bt * 3072 + (w << 10) + (h << 6) + lane;

    const float x = bf2f(qkv[idx]);
    float ss = x * x;
    #pragma unroll
    for (int m = 1; m < 64; m <<= 1) ss += __shfl_xor(ss, m, 64);
    const float rn = rsqrtf(ss * (1.0f / 64.0f) + EPSV);
    const float xn = x * rn;
    const float other = __shfl_xor(xn, 32, 64);
    const float rot = (lane < 32) ? -other : other;
    const float c = cosp[tpos * 64 + lane];
    const float s = sinp[tpos * 64 + lane];
    const float scale = (w == 0) ? 0.18033688011112042f : 1.0f;  // log2e/8
    qkv[idx] = f2bf(fmaf(xn, c, rot * s) * scale);
}

// ======================================================================
// V transpose: qkv v-slice [b,t,h,d] -> vt [b,h,d,t]. 64x64 tiles.
// ======================================================================
__global__ __launch_bounds__(256) void v_transpose(
    const unsigned short* __restrict__ qkv, unsigned short* __restrict__ vt,
    int T)
{
    __shared__ unsigned short tile[64][72];
    const int bh = blockIdx.x;
    const int b  = bh >> 4, h = bh & 15;
    const int t0 = blockIdx.y << 6;
    const int t  = threadIdx.x;
    const unsigned short* vbase = qkv + (size_t)b * T * 3072 + 2048 + (h << 6);

    #pragma unroll
    for (int i = 0; i < 2; ++i) {
        const int c = t + (i << 8);
        const int r = c >> 3, c8 = (c & 7) << 3;
        const short8 v = *(const short8*)&vbase[(size_t)(t0 + r) * 3072 + c8];
        #pragma unroll
        for (int j = 0; j < 8; ++j)
            tile[c8 + j][r] = (unsigned short)v[j];
    }
    __syncthreads();
    #pragma unroll
    for (int i = 0; i < 2; ++i) {
        const int c = t + (i << 8);
        const int d = c >> 3, c8 = (c & 7) << 3;
        const short8 o = *(const short8*)&tile[d][c8];
        *(short8*)&vt[((size_t)bh * 64 + d) * T + t0 + c8] = o;
    }
}

// ======================================================================
// Barrier-free MFMA flash attention. Block = (b,h) x 64 q-rows, 4 waves;
// wave w owns q-rows [q0+16w, q0+16w+15] and is fully independent:
// K / V^T fragments are loaded b128 directly from global (L2-resident;
// (col,quad) layout covers whole 64B lines), P round-trips through a
// PER-WAVE LDS buffer -> zero __syncthreads. Each wave stops at its own
// diagonal. Softmax in exp2 domain (q pre-scaled by log2e/8).
// ======================================================================
__global__ __launch_bounds__(256) void flash_attn_mfma(
    const unsigned short* __restrict__ qkv,
    const unsigned short* __restrict__ vt,
    unsigned short* __restrict__ yb,
    int B, int T)
{
    const int bh = blockIdx.x;
    const int b  = bh >> 4, h = bh & 15;
    const int q0 = ((int)gridDim.y - 1 - (int)blockIdx.y) << 6;  // heavy first
    const int t  = threadIdx.x;
    const int lane = t & 63;
    const int w    = t >> 6;
    const int col  = lane & 15;
    const int quad = lane >> 4;

    __shared__ unsigned short Ps[4][16][72];   // per-wave [q-col][s]

    const unsigned short* qb  = qkv + (size_t)b * T * 3072 + (h << 6);
    const unsigned short* kb  = qb + 1024;
    const unsigned short* vtb = vt + (size_t)bh * 64 * T;

    const int qw = q0 + w * 16;        // wave's first q row
    const int qg = qw + col;           // lane's q row

    // ---- Q B-frags: direct b128 loads (pre-scaled in rmsnorm_rope) ----
    short8 qf[2];
    {
        const unsigned short* qrow = qb + (size_t)qg * 3072 + (quad << 3);
        qf[0] = *(const short8*)&qrow[0];
        qf[1] = *(const short8*)&qrow[32];
    }

    f32x4 oacc[4];
    #pragma unroll
    for (int i = 0; i < 4; ++i) oacc[i] = (f32x4){0.f, 0.f, 0.f, 0.f};
    float m_i = -INFINITY, l_i = 0.f;

    unsigned short* pw = &Ps[w][col][0];
    const unsigned short* kfrag = kb + (size_t)col * 3072 + (quad << 3);
    const unsigned short* vfrag = vtb + (size_t)col * T + (quad << 3);

    const int last_kt = (qw + 15) >> 6;
    for (int kt = 0; kt <= last_kt; ++kt) {
        const int k0 = kt << 6;

        // ---- K frags direct from global ----
        short8 kf[2][4];
        {
            const unsigned short* kp = kfrag + (size_t)k0 * 3072;
            #pragma unroll
            for (int mt = 0; mt < 4; ++mt) {
                kf[0][mt] = *(const short8*)&kp[(size_t)(mt * 16) * 3072];
                kf[1][mt] = *(const short8*)&kp[(size_t)(mt * 16) * 3072 + 32];
            }
        }

        // ---- S^T = K @ Q^T ----
        f32x4 st[4];
        #pragma unroll
        for (int i = 0; i < 4; ++i) st[i] = (f32x4){0.f, 0.f, 0.f, 0.f};
        #pragma unroll
        for (int ks = 0; ks < 2; ++ks)
            #pragma unroll
            for (int mt = 0; mt < 4; ++mt)
                st[mt] = __builtin_amdgcn_mfma_f32_16x16x32_bf16(
                    kf[ks][mt], qf[ks], st[mt], 0, 0, 0);

        // ---- mask + online softmax (per-lane state; col = q) ----
        float sv[4][4];
        float mloc = -INFINITY;
        if (k0 + 63 > qw) {                       // diagonal tile
            #pragma unroll
            for (int mt = 0; mt < 4; ++mt) {
                const int sbase = k0 + mt * 16 + (quad << 2);
                #pragma unroll
                for (int r = 0; r < 4; ++r) {
                    float x = st[mt][r];
                    if (sbase + r > qg) x = -INFINITY;
                    sv[mt][r] = x;
                    mloc = fmaxf(mloc, x);
                }
            }
        } else {
            #pragma unroll
            for (int mt = 0; mt < 4; ++mt)
                #pragma unroll
                for (int r = 0; r < 4; ++r) {
                    sv[mt][r] = st[mt][r];
                    mloc = fmaxf(mloc, st[mt][r]);
                }
        }
        mloc = fmaxf(mloc, __shfl_xor(mloc, 16, 64));
        mloc = fmaxf(mloc, __shfl_xor(mloc, 32, 64));
        const float mnew  = fmaxf(m_i, mloc);
        const float alpha = __builtin_amdgcn_exp2f(m_i - mnew);
        float rs = 0.f;
        #pragma unroll
        for (int mt = 0; mt < 4; ++mt) {
            const float p0 = __builtin_amdgcn_exp2f(sv[mt][0] - mnew);
            const float p1 = __builtin_amdgcn_exp2f(sv[mt][1] - mnew);
            const float p2 = __builtin_amdgcn_exp2f(sv[mt][2] - mnew);
            const float p3 = __builtin_amdgcn_exp2f(sv[mt][3] - mnew);
            rs += (p0 + p1) + (p2 + p3);
            uint2 pk;
            pk.x = pack_bf16_ru(p0, p1);
            pk.y = pack_bf16_ru(p2, p3);
            *(uint2*)&pw[mt * 16 + (quad << 2)] = pk;
        }
        rs += __shfl_xor(rs, 16, 64);
        rs += __shfl_xor(rs, 32, 64);
        l_i = l_i * alpha + rs;
        m_i = mnew;
        #pragma unroll
        for (int mt = 0; mt < 4; ++mt) {
            oacc[mt][0] *= alpha; oacc[mt][1] *= alpha;
            oacc[mt][2] *= alpha; oacc[mt][3] *= alpha;
        }

        // ---- O^T += V^T @ P^T (V^T frags direct from global) ----
        #pragma unroll
        for (int ks = 0; ks < 2; ++ks) {
            const short8 pf = *(const short8*)&pw[ks * 32 + (quad << 3)];
            #pragma unroll
            for (int mt = 0; mt < 4; ++mt) {
                const short8 vf = *(const short8*)&vfrag[(size_t)(mt * 16) * T + k0 + (ks << 5)];
                oacc[mt] = __builtin_amdgcn_mfma_f32_16x16x32_bf16(
                    vf, pf, oacc[mt], 0, 0, 0);
            }
        }
    }

    // ---- epilogue: normalize, store y[b,t,h,d] (bf16) ----
    const float inv = 1.0f / l_i;
    unsigned short* yrow = yb + (size_t)(b * T + qg) * 1024 + (h << 6);
    #pragma unroll
    for (int mt = 0; mt < 4; ++mt) {
        ushort4 yv;
        yv.x = f2bf(oacc[mt][0] * inv);
        yv.y = f2bf(oacc[mt][1] * inv);
        yv.z = f2bf(oacc[mt][2] * inv);
        yv.w = f2bf(oacc[mt][3] * inv);
        *(ushort4*)&yrow[mt * 16 + (quad << 2)] = yv;
    }
}

// ======================================================================
extern "C" void kernel_launch(void* const* d_in, const int* in_sizes, int n_in,
                              void* d_out, int out_size, void* d_ws, size_t ws_size,
                              hipStream_t stream)
{
    const float* x      = (const float*)d_in[0];
    const float* cosp   = (const float*)d_in[1];
    const float* sinp   = (const float*)d_in[2];
    const float* W_attn = (const float*)d_in[3];
    const float* b_attn = (const float*)d_in[4];
    const float* W_proj = (const float*)d_in[5];
    const float* b_proj = (const float*)d_in[6];
    float* out = (float*)d_out;

    const int C = 1024, H = 16;
    const int T  = in_sizes[1] / 64;     // cos: (T, 64)
    const int BT = in_sizes[0] / C;      // B*T
    const int B  = BT / T;

    unsigned short* qkvb = (unsigned short*)d_ws;              // BT*3072
    unsigned short* xb   = qkvb + (size_t)BT * 3072;           // BT*1024
    unsigned short* Wab  = xb   + (size_t)BT * 1024;           // 3072*1024
    unsigned short* Wpb  = Wab  + (size_t)3072 * 1024;         // 1024*1024
    unsigned short* yb   = Wpb  + (size_t)1024 * 1024;         // BT*1024
    unsigned short* vtb  = xb;   // vt aliases xb (x dead after gemm1)

    cast_bf16<<<dim3(BT * C / 1024), dim3(256), 0, stream>>>(x, xb, BT * C);
    transpose_cast<<<dim3(3 * C / 32, C / 32), dim3(256), 0, stream>>>(W_attn, Wab, C, 3 * C);
    transpose_cast<<<dim3(C / 32, C / 32), dim3(256), 0, stream>>>(W_proj, Wpb, C, C);

    gemm_bf16<true><<<dim3(3 * C / 128, BT / 128), dim3(256), 0, stream>>>(
        xb, Wab, b_attn, qkvb, BT, 3 * C, C);

    rmsnorm_rope<<<dim3(BT * H * 2 / 4), dim3(256), 0, stream>>>(
        qkvb, cosp, sinp, BT, T);

    v_transpose<<<dim3(B * H, T / 64), dim3(256), 0, stream>>>(qkvb, vtb, T);

    flash_attn_mfma<<<dim3(B * H, T / 64), dim3(256), 0, stream>>>(
        qkvb, vtb, yb, B, T);

    gemm_bf16<false><<<dim3(C / 128, BT / 128), dim3(256), 0, stream>>>(
        yb, Wpb, b_proj, out, BT, C, C);
}

// Round 6
// 225.235 us; speedup vs baseline: 1.3940x; 1.3940x over previous
//
#include <hip/hip_runtime.h>
#include <math.h>

#define EPSV 1.1920929e-07f

typedef __attribute__((ext_vector_type(8))) short short8;
typedef __attribute__((ext_vector_type(4))) float f32x4;

__device__ __forceinline__ float bf2f(unsigned short u) {
    union { unsigned int i; float f; } c; c.i = ((unsigned int)u) << 16; return c.f;
}
__device__ __forceinline__ unsigned short f2bf(float f) {
    union { float f; unsigned int i; } c; c.f = f;
    unsigned int r = c.i + 0x7FFFu + ((c.i >> 16) & 1u);   // RNE
    return (unsigned short)(r >> 16);
}
// pack two f32 -> two bf16 (round-half-up) in one u32: low=a, high=b
__device__ __forceinline__ unsigned int pack_bf16_ru(float a, float b) {
    union { float f; unsigned int i; } ca, cb; ca.f = a; cb.f = b;
    return __builtin_amdgcn_perm(cb.i + 0x8000u, ca.i + 0x8000u, 0x07060302u);
}
// async global -> LDS, 16 B per lane (dest = wave-uniform base + lane*16)
__device__ __forceinline__ void async_lds16(const unsigned short* g, unsigned short* l) {
    __builtin_amdgcn_global_load_lds(
        (const __attribute__((address_space(1))) unsigned int*)g,
        (__attribute__((address_space(3))) unsigned int*)l, 16, 0, 0);
}

// ======================================================================
// cast fp32 -> bf16 elementwise. 4 elems/thread.
// ======================================================================
__global__ __launch_bounds__(256) void cast_bf16(
    const float* __restrict__ src, unsigned short* __restrict__ dst, int n)
{
    const int i = (blockIdx.x * 256 + threadIdx.x) * 4;
    if (i >= n) return;
    const float4 v = *(const float4*)&src[i];
    ushort4 o;
    o.x = f2bf(v.x); o.y = f2bf(v.y); o.z = f2bf(v.z); o.w = f2bf(v.w);
    *(ushort4*)&dst[i] = o;
}

// ======================================================================
// transpose + cast: W [K][N] fp32 -> Wt [N][K] bf16. 32x32 tiles.
// ======================================================================
__global__ __launch_bounds__(256) void transpose_cast(
    const float* __restrict__ W, unsigned short* __restrict__ Wt, int K, int N)
{
    __shared__ float tile[32][33];
    const int n0 = blockIdx.x * 32, k0 = blockIdx.y * 32;
    const int r = threadIdx.x >> 3, c4 = (threadIdx.x & 7) * 4;
    const float4 v = *(const float4*)&W[(size_t)(k0 + r) * N + n0 + c4];
    tile[r][c4 + 0] = v.x; tile[r][c4 + 1] = v.y;
    tile[r][c4 + 2] = v.z; tile[r][c4 + 3] = v.w;
    __syncthreads();
    ushort4 o;
    o.x = f2bf(tile[c4 + 0][r]); o.y = f2bf(tile[c4 + 1][r]);
    o.z = f2bf(tile[c4 + 2][r]); o.w = f2bf(tile[c4 + 3][r]);
    *(ushort4*)&Wt[(size_t)(n0 + r) * K + k0 + c4] = o;
}

// ======================================================================
// bf16 MFMA GEMM, m97 structure: C[M,N] = A[M,K] @ Bt[N,K]^T + bias[N]
// 128x128x32 tile; global_load_lds width-16 staging into unpadded
// [128][32] LDS (dest = wave base + lane*16, matched layout).
// ======================================================================
template <bool OUT_BF16>
__global__ __launch_bounds__(256) void gemm_bf16(
    const unsigned short* __restrict__ A,
    const unsigned short* __restrict__ Bt,
    const float* __restrict__ bias,
    void* __restrict__ Cv,
    int M, int N, int K)
{
    __shared__ unsigned short As[128][32];
    __shared__ unsigned short Bs[128][32];
    const int t    = threadIdx.x;
    const int lane = t & 63;
    const int wv   = t >> 6;
    const int wrow = (wv >> 1) * 64;
    const int wcol = (wv & 1) * 64;
    const int m0 = blockIdx.y * 128;
    const int n0 = blockIdx.x * 128;
    const int col  = lane & 15;
    const int quad = lane >> 4;

    const int srow = (wv << 5) + (lane >> 2);     // wv*32 + 0..15
    const int scol = (lane & 3) << 3;             // 0,8,16,24
    const unsigned short* ap0 = A  + (size_t)(m0 + srow) * K + scol;
    const unsigned short* ap1 = ap0 + (size_t)16 * K;
    const unsigned short* bp0 = Bt + (size_t)(n0 + srow) * K + scol;
    const unsigned short* bp1 = bp0 + (size_t)16 * K;
    unsigned short* al0 = &As[srow][scol];
    unsigned short* al1 = &As[srow + 16][scol];
    unsigned short* bl0 = &Bs[srow][scol];
    unsigned short* bl1 = &Bs[srow + 16][scol];

    f32x4 acc[4][4];
    #pragma unroll
    for (int i = 0; i < 4; ++i)
        #pragma unroll
        for (int j = 0; j < 4; ++j)
            acc[i][j] = (f32x4){0.f, 0.f, 0.f, 0.f};

    for (int k0 = 0; k0 < K; k0 += 32) {
        async_lds16(ap0, al0);
        async_lds16(ap1, al1);
        async_lds16(bp0, bl0);
        async_lds16(bp1, bl1);
        ap0 += 32; ap1 += 32; bp0 += 32; bp1 += 32;
        __syncthreads();
        short8 af[4], bf[4];
        #pragma unroll
        for (int mt = 0; mt < 4; ++mt)
            af[mt] = *(const short8*)&As[wrow + mt * 16 + col][quad << 3];
        #pragma unroll
        for (int nt = 0; nt < 4; ++nt)
            bf[nt] = *(const short8*)&Bs[wcol + nt * 16 + col][quad << 3];
        #pragma unroll
        for (int mt = 0; mt < 4; ++mt)
            #pragma unroll
            for (int nt = 0; nt < 4; ++nt)
                acc[mt][nt] = __builtin_amdgcn_mfma_f32_16x16x32_bf16(
                    af[mt], bf[nt], acc[mt][nt], 0, 0, 0);
        __syncthreads();
    }

    const int rowq = quad << 2;
    #pragma unroll
    for (int nt = 0; nt < 4; ++nt) {
        const int n = n0 + wcol + nt * 16 + col;
        const float bv = bias[n];
        #pragma unroll
        for (int mt = 0; mt < 4; ++mt) {
            #pragma unroll
            for (int r = 0; r < 4; ++r) {
                const int m = m0 + wrow + mt * 16 + rowq + r;
                const float v = acc[mt][nt][r] + bv;
                if (OUT_BF16)
                    ((unsigned short*)Cv)[(size_t)m * N + n] = f2bf(v);
                else
                    ((float*)Cv)[(size_t)m * N + n] = v;
            }
        }
    }
}

// ======================================================================
// RMSNorm (D=64) then rotary, in-place on bf16 q/k slices.
// q output pre-scaled by log2e/8 (folds softmax scale -> exp2 domain).
// ======================================================================
__global__ __launch_bounds__(256) void rmsnorm_rope(
    unsigned short* __restrict__ qkv, const float* __restrict__ cosp,
    const float* __restrict__ sinp, int BT, int T)
{
    const int wid  = (blockIdx.x << 2) + (threadIdx.x >> 6);
    const int lane = threadIdx.x & 63;
    const int w  = wid & 1;
    const int h  = (wid >> 1) & 15;
    const int bt = wid >> 5;
    if (bt >= BT) return;
    const int tpos = bt % T;
    const size_t idx = (size_t)bt * 3072 + (w << 10) + (h << 6) + lane;

    const float x = bf2f(qkv[idx]);
    float ss = x * x;
    #pragma unroll
    for (int m = 1; m < 64; m <<= 1) ss += __shfl_xor(ss, m, 64);
    const float rn = rsqrtf(ss * (1.0f / 64.0f) + EPSV);
    const float xn = x * rn;
    const float other = __shfl_xor(xn, 32, 64);
    const float rot = (lane < 32) ? -other : other;
    const float c = cosp[tpos * 64 + lane];
    const float s = sinp[tpos * 64 + lane];
    const float scale = (w == 0) ? 0.18033688011112042f : 1.0f;  // log2e/8
    qkv[idx] = f2bf(fmaf(xn, c, rot * s) * scale);
}

// ======================================================================
// V transpose: qkv v-slice [b,t,h,d] -> vt [b,h,d,t]. 64x64 tiles.
// ======================================================================
__global__ __launch_bounds__(256) void v_transpose(
    const unsigned short* __restrict__ qkv, unsigned short* __restrict__ vt,
    int T)
{
    __shared__ unsigned short tile[64][72];
    const int bh = blockIdx.x;
    const int b  = bh >> 4, h = bh & 15;
    const int t0 = blockIdx.y << 6;
    const int t  = threadIdx.x;
    const unsigned short* vbase = qkv + (size_t)b * T * 3072 + 2048 + (h << 6);

    #pragma unroll
    for (int i = 0; i < 2; ++i) {
        const int c = t + (i << 8);
        const int r = c >> 3, c8 = (c & 7) << 3;
        const short8 v = *(const short8*)&vbase[(size_t)(t0 + r) * 3072 + c8];
        #pragma unroll
        for (int j = 0; j < 8; ++j)
            tile[c8 + j][r] = (unsigned short)v[j];
    }
    __syncthreads();
    #pragma unroll
    for (int i = 0; i < 2; ++i) {
        const int c = t + (i << 8);
        const int d = c >> 3, c8 = (c & 7) << 3;
        const short8 o = *(const short8*)&tile[d][c8];
        *(short8*)&vt[((size_t)bh * 64 + d) * T + t0 + c8] = o;
    }
}

// ======================================================================
// MFMA flash attention, r3 skeleton + VALU diet. Block = (b,h) x 64
// q-rows, 4 waves; K/V^T staged in LDS per 64-s tile (2 barriers/kt).
// S^T = K Q^T (per-lane softmax state, col = q); PV as O^T = V^T P^T.
// exp2-domain softmax (q pre-scaled by log2e/8 in rmsnorm_rope).
// LDS rows padded to 72 shorts.
// ======================================================================
__global__ __launch_bounds__(256) void flash_attn_mfma(
    const unsigned short* __restrict__ qkv,
    const unsigned short* __restrict__ vt,
    unsigned short* __restrict__ yb,
    int B, int T)
{
    const int bh = blockIdx.x;
    const int b  = bh >> 4, h = bh & 15;
    const int q0 = ((int)gridDim.y - 1 - (int)blockIdx.y) << 6;  // heavy first
    const int t  = threadIdx.x;
    const int lane = t & 63;
    const int w    = t >> 6;
    const int col  = lane & 15;
    const int quad = lane >> 4;

    __shared__ unsigned short Ks [64][72];
    __shared__ unsigned short Vts[64][72];
    __shared__ unsigned short Ps [4][16][72];   // per-wave [q-col][s]

    const unsigned short* qb  = qkv + (size_t)b * T * 3072 + (h << 6);
    const unsigned short* kb  = qb + 1024;
    const unsigned short* vtb = vt + (size_t)bh * 64 * T;

    const int qw = q0 + w * 16;        // wave's first q row
    const int qg = qw + col;           // lane's q row

    // ---- Q B-frags: direct b128 loads (pre-scaled by log2e/8) ----
    short8 qf[2];
    {
        const unsigned short* qrow = qb + (size_t)qg * 3072 + (quad << 3);
        qf[0] = *(const short8*)&qrow[0];
        qf[1] = *(const short8*)&qrow[32];
    }

    f32x4 oacc[4];
    #pragma unroll
    for (int i = 0; i < 4; ++i) oacc[i] = (f32x4){0.f, 0.f, 0.f, 0.f};
    float m_i = -INFINITY, l_i = 0.f;

    // ---- hoisted staging pointers (+const increments per kt) ----
    const int sr = t >> 3, sc = (t & 7) << 3;   // 32 rows x 64 cols per pass
    const unsigned short* kp0 = kb  + (size_t)sr * 3072 + sc;
    const unsigned short* kp1 = kp0 + (size_t)32 * 3072;
    const unsigned short* vp0 = vtb + (size_t)sr * T + sc;
    const unsigned short* vp1 = vp0 + (size_t)32 * T;
    unsigned short* kw0 = &Ks[sr][sc];
    unsigned short* kw1 = &Ks[sr + 32][sc];
    unsigned short* vw0 = &Vts[sr][sc];
    unsigned short* vw1 = &Vts[sr + 32][sc];
    unsigned short* pw  = &Ps[w][col][0];

    const int last_kt = q0 >> 6;
    for (int kt = 0; kt <= last_kt; ++kt) {
        const int k0 = kt << 6;
        __syncthreads();   // prev compute done reading LDS
        *(short8*)kw0 = *(const short8*)kp0;
        *(short8*)kw1 = *(const short8*)kp1;
        *(short8*)vw0 = *(const short8*)vp0;
        *(short8*)vw1 = *(const short8*)vp1;
        kp0 += 64 * 3072; kp1 += 64 * 3072; vp0 += 64; vp1 += 64;
        __syncthreads();

        // ---- S^T = K @ Q^T ----
        f32x4 st[4];
        #pragma unroll
        for (int i = 0; i < 4; ++i) st[i] = (f32x4){0.f, 0.f, 0.f, 0.f};
        #pragma unroll
        for (int ks = 0; ks < 2; ++ks)
            #pragma unroll
            for (int mt = 0; mt < 4; ++mt) {
                const short8 kf = *(const short8*)&Ks[mt * 16 + col][ks * 32 + (quad << 3)];
                st[mt] = __builtin_amdgcn_mfma_f32_16x16x32_bf16(kf, qf[ks], st[mt], 0, 0, 0);
            }

        // ---- mask + online softmax (exp2 domain; per-lane, col = q) ----
        float sv[4][4];
        float mloc = -INFINITY;
        if (k0 + 63 > qw) {                       // diagonal tile
            #pragma unroll
            for (int mt = 0; mt < 4; ++mt) {
                const int sbase = k0 + mt * 16 + (quad << 2);
                #pragma unroll
                for (int r = 0; r < 4; ++r) {
                    float x = st[mt][r];
                    if (sbase + r > qg) x = -INFINITY;
                    sv[mt][r] = x;
                    mloc = fmaxf(mloc, x);
                }
            }
        } else {
            #pragma unroll
            for (int mt = 0; mt < 4; ++mt)
                #pragma unroll
                for (int r = 0; r < 4; ++r) {
                    sv[mt][r] = st[mt][r];
                    mloc = fmaxf(mloc, st[mt][r]);
                }
        }
        mloc = fmaxf(mloc, __shfl_xor(mloc, 16, 64));
        mloc = fmaxf(mloc, __shfl_xor(mloc, 32, 64));
        const float mnew  = fmaxf(m_i, mloc);
        const float alpha = __builtin_amdgcn_exp2f(m_i - mnew);
        float rs = 0.f;
        #pragma unroll
        for (int mt = 0; mt < 4; ++mt) {
            const float p0 = __builtin_amdgcn_exp2f(sv[mt][0] - mnew);
            const float p1 = __builtin_amdgcn_exp2f(sv[mt][1] - mnew);
            const float p2 = __builtin_amdgcn_exp2f(sv[mt][2] - mnew);
            const float p3 = __builtin_amdgcn_exp2f(sv[mt][3] - mnew);
            rs += (p0 + p1) + (p2 + p3);
            uint2 pk;
            pk.x = pack_bf16_ru(p0, p1);
            pk.y = pack_bf16_ru(p2, p3);
            *(uint2*)&pw[mt * 16 + (quad << 2)] = pk;
        }
        rs += __shfl_xor(rs, 16, 64);
        rs += __shfl_xor(rs, 32, 64);
        l_i = l_i * alpha + rs;
        m_i = mnew;
        #pragma unroll
        for (int mt = 0; mt < 4; ++mt) {
            oacc[mt][0] *= alpha; oacc[mt][1] *= alpha;
            oacc[mt][2] *= alpha; oacc[mt][3] *= alpha;
        }

        // ---- O^T += V^T @ P^T ----
        #pragma unroll
        for (int ks = 0; ks < 2; ++ks) {
            const short8 pf = *(const short8*)&pw[ks * 32 + (quad << 3)];
            #pragma unroll
            for (int mt = 0; mt < 4; ++mt) {
                const short8 vf = *(const short8*)&Vts[mt * 16 + col][ks * 32 + (quad << 3)];
                oacc[mt] = __builtin_amdgcn_mfma_f32_16x16x32_bf16(vf, pf, oacc[mt], 0, 0, 0);
            }
        }
    }

    // ---- epilogue: normalize, store y[b,t,h,d] (bf16) ----
    const float inv = 1.0f / l_i;
    unsigned short* yrow = yb + (size_t)(b * T + qg) * 1024 + (h << 6);
    #pragma unroll
    for (int mt = 0; mt < 4; ++mt) {
        ushort4 yv;
        yv.x = f2bf(oacc[mt][0] * inv);
        yv.y = f2bf(oacc[mt][1] * inv);
        yv.z = f2bf(oacc[mt][2] * inv);
        yv.w = f2bf(oacc[mt][3] * inv);
        *(ushort4*)&yrow[mt * 16 + (quad << 2)] = yv;
    }
}

// ======================================================================
extern "C" void kernel_launch(void* const* d_in, const int* in_sizes, int n_in,
                              void* d_out, int out_size, void* d_ws, size_t ws_size,
                              hipStream_t stream)
{
    const float* x      = (const float*)d_in[0];
    const float* cosp   = (const float*)d_in[1];
    const float* sinp   = (const float*)d_in[2];
    const float* W_attn = (const float*)d_in[3];
    const float* b_attn = (const float*)d_in[4];
    const float* W_proj = (const float*)d_in[5];
    const float* b_proj = (const float*)d_in[6];
    float* out = (float*)d_out;

    const int C = 1024, H = 16;
    const int T  = in_sizes[1] / 64;     // cos: (T, 64)
    const int BT = in_sizes[0] / C;      // B*T
    const int B  = BT / T;

    unsigned short* qkvb = (unsigned short*)d_ws;              // BT*3072
    unsigned short* xb   = qkvb + (size_t)BT * 3072;           // BT*1024
    unsigned short* Wab  = xb   + (size_t)BT * 1024;           // 3072*1024
    unsigned short* Wpb  = Wab  + (size_t)3072 * 1024;         // 1024*1024
    unsigned short* yb   = Wpb  + (size_t)1024 * 1024;         // BT*1024
    unsigned short* vtb  = xb;   // vt aliases xb (x dead after gemm1)

    cast_bf16<<<dim3(BT * C / 1024), dim3(256), 0, stream>>>(x, xb, BT * C);
    transpose_cast<<<dim3(3 * C / 32, C / 32), dim3(256), 0, stream>>>(W_attn, Wab, C, 3 * C);
    transpose_cast<<<dim3(C / 32, C / 32), dim3(256), 0, stream>>>(W_proj, Wpb, C, C);

    gemm_bf16<true><<<dim3(3 * C / 128, BT / 128), dim3(256), 0, stream>>>(
        xb, Wab, b_attn, qkvb, BT, 3 * C, C);

    rmsnorm_rope<<<dim3(BT * H * 2 / 4), dim3(256), 0, stream>>>(
        qkvb, cosp, sinp, BT, T);

    v_transpose<<<dim3(B * H, T / 64), dim3(256), 0, stream>>>(qkvb, vtb, T);

    flash_attn_mfma<<<dim3(B * H, T / 64), dim3(256), 0, stream>>>(
        qkvb, vtb, yb, B, T);

    gemm_bf16<false><<<dim3(C / 128, BT / 128), dim3(256), 0, stream>>>(
        yb, Wpb, b_proj, out, BT, C, C);
}